// Round 10
// baseline (385.034 us; speedup 1.0000x reference)
//
#include <hip/hip_runtime.h>
#include <hip/hip_bf16.h>

typedef short bh8 __attribute__((ext_vector_type(8)));
typedef float f32x4 __attribute__((ext_vector_type(4)));
typedef uint u32x4 __attribute__((ext_vector_type(4)));

#define NBLOCKS_MAIN 512
#define EPB 4096           // edges per sort-block
#define MAXB 1280          // max buckets (LDS arrays)

__device__ __forceinline__ short f2bf(float f) {
  __hip_bfloat16 h = __float2bfloat16(f);
  return *reinterpret_cast<short*>(&h);
}
__device__ __forceinline__ float bf2f(short s) {
  return __uint_as_float(((uint)(ushort)s) << 16);
}
__device__ __forceinline__ int fpos(int f) {
  int kf = (f >> 5) & 3, h = (f >> 4) & 1, q = (f >> 2) & 3, j = f & 3;
  return (kf << 5) | (q << 3) | (h << 2) | j;
}
__device__ __forceinline__ int get_xcd() {
  uint x;
  asm volatile("s_getreg_b32 %0, hwreg(HW_REG_XCC_ID)" : "=s"(x));
  return (int)(x & 7u);
}

// ---- kernel 1: per-node Pa = z@W1a + b1, Pb = z@W1b, bf16 frag-permuted ----
__global__ __launch_bounds__(256) void precompute_p(
    const float* __restrict__ z, const float* __restrict__ W1,
    const float* __restrict__ b1, ushort* __restrict__ Pa,
    ushort* __restrict__ Pb, int NN) {
  __shared__ float zs[4][128];
  const int tid = threadIdx.x;
  const int n0 = blockIdx.x * 4;
  for (int i = tid; i < 512; i += 256) {
    int m = i >> 7, ff = i & 127, n = n0 + m;
    zs[m][ff] = (n < NN) ? z[n * 128 + ff] : 0.f;
  }
  __syncthreads();
  const int f = tid & 127;
  const bool isA = tid < 128;
  const float* w = W1 + (isA ? 0 : 128) * 128 + f;
  float a0, a1, a2, a3;
  a0 = a1 = a2 = a3 = isA ? b1[f] : 0.f;
#pragma unroll 16
  for (int k = 0; k < 128; ++k) {
    float wv = w[(size_t)k * 128];
    a0 += zs[0][k] * wv; a1 += zs[1][k] * wv;
    a2 += zs[2][k] * wv; a3 += zs[3][k] * wv;
  }
  ushort* dst = isA ? Pa : Pb;
  int pos = fpos(f);
  float av[4] = {a0, a1, a2, a3};
#pragma unroll
  for (int m = 0; m < 4; ++m)
    if (n0 + m < NN) dst[(size_t)(n0 + m) * 128 + pos] = (ushort)f2bf(av[m]);
}

// ---- kernel 2: pack W2/W3 into frag-linear bf16 ----
__global__ __launch_bounds__(512) void pack_w(
    const float* __restrict__ W2, const float* __restrict__ W3,
    ushort* __restrict__ w2f, ushort* __restrict__ w3f) {
  int idx = blockIdx.x * 512 + threadIdx.x;
  if (idx >= 16384) return;
  int e = idx & 7, l = (idx >> 3) & 63, kb = (idx >> 9) & 3, ob = idx >> 11;
  int q = l >> 4;
  int k = kb * 32 + (e < 4 ? q * 4 + e : 16 + q * 4 + (e - 4));
  int n = ob * 16 + (l & 15);
  w2f[idx] = (ushort)f2bf(W2[k * 128 + n]);
  w3f[idx] = (ushort)f2bf(W3[k * 128 + n]);
}

__device__ __forceinline__ int edge_key(int s, int d, int NN) {
  return ((s >> 5) << 1) | ((2 * d >= NN) ? 1 : 0);   // 32-node src buckets x dst half
}

// ---- kernel 3: per-block bucket histogram (LDS atomics only) ----
__global__ __launch_bounds__(256) void histB(
    const int* __restrict__ ei, int* __restrict__ H, int E, int NN, int NB) {
  __shared__ int h[MAXB];
  const int tid = threadIdx.x, j = blockIdx.x;
  for (int b = tid; b < NB; b += 256) h[b] = 0;
  __syncthreads();
#pragma unroll
  for (int r = 0; r < EPB / 256; ++r) {
    int e = j * EPB + r * 256 + tid;
    if (e < E) {
      int s = __builtin_nontemporal_load(ei + e);
      int d = __builtin_nontemporal_load(ei + E + e);
      atomicAdd(&h[edge_key(s, d, NN)], 1);
    }
  }
  __syncthreads();
  for (int b = tid; b < NB; b += 256) H[(size_t)j * NB + b] = h[b];
}

// ---- kernel 4a: per-bucket column exclusive scan over blocks (wave/bucket) ----
__global__ __launch_bounds__(512) void scanA(
    int* __restrict__ H, int* __restrict__ total, int NB, int NSB) {
  const int w = threadIdx.x >> 6, lane = threadIdx.x & 63;
  const int b = blockIdx.x * 8 + w;
  if (b >= NB) return;
  int run = 0;
  for (int base = 0; base < NSB; base += 64) {
    int j = base + lane;
    int v = (j < NSB) ? H[(size_t)j * NB + b] : 0;
    int inc = v;
#pragma unroll
    for (int dd = 1; dd < 64; dd <<= 1) {
      int u = __shfl_up(inc, dd, 64);
      if (lane >= dd) inc += u;
    }
    if (j < NSB) H[(size_t)j * NB + b] = run + inc - v;
    run += __shfl(inc, 63, 64);
  }
  if (lane == 0) total[b] = run;
}

// ---- kernel 4b: scan bucket totals -> base[]; queue reset ----
__global__ __launch_bounds__(1024) void scanB(
    const int* __restrict__ total, int* __restrict__ base,
    int* __restrict__ queue, int NB) {
  const int tid = threadIdx.x, lane = tid & 63, w = tid >> 6;
  __shared__ int wsum[16], woff[17];
  int v = (tid < NB) ? total[tid] : 0;   // NB <= 1024
  int inc = v;
#pragma unroll
  for (int dd = 1; dd < 64; dd <<= 1) {
    int u = __shfl_up(inc, dd, 64);
    if (lane >= dd) inc += u;
  }
  if (lane == 63) wsum[w] = inc;
  __syncthreads();
  if (tid == 0) {
    int a = 0;
#pragma unroll
    for (int k = 0; k < 16; ++k) { woff[k] = a; a += wsum[k]; }
    woff[16] = a;
  }
  __syncthreads();
  int ex = woff[w] + inc - v;
  if (tid <= NB) base[tid] = (tid < NB) ? ex : woff[16];
  if (tid < 8) queue[tid] = 0;
}

// ---- kernel 5: scatter into bucket order + pre-gather graph + perm ----
__global__ __launch_bounds__(256) void scatterB(
    const int* __restrict__ ei, const float* __restrict__ graph,
    const int* __restrict__ H, const int* __restrict__ base,
    u32x4* __restrict__ packed, int* __restrict__ perm,
    int E, int NN, int NB) {
  __shared__ int cur[MAXB];
  const int tid = threadIdx.x, j = blockIdx.x;
  for (int b = tid; b < NB; b += 256)
    cur[b] = H[(size_t)j * NB + b] + base[b];
  __syncthreads();
#pragma unroll
  for (int r = 0; r < EPB / 256; ++r) {
    int e = j * EPB + r * 256 + tid;
    if (e < E) {
      int s = __builtin_nontemporal_load(ei + e);
      int d = __builtin_nontemporal_load(ei + E + e);
      float g = __builtin_nontemporal_load(graph + (size_t)s * NN + d);
      int pos = atomicAdd(&cur[edge_key(s, d, NN)], 1);
      u32x4 pk = {(uint)s, (uint)d, __float_as_uint(g), 0u};
      packed[pos] = pk;
      perm[e] = pos;
    }
  }
}

// ---- kernel 6: main edge MLP, bucket-quantum XCD queues, Pa from LDS ----
struct alignas(16) SMem {
  ushort w2[16384];      // frag-linear: ((ob*4+kf)*64+lane)*8+e
  ushort w3[16384];
  ushort pa[32][128];    // Pa slice for current bucket, seg-swizzled
  float b2[128], b3[128], w4[128];
  ushort w1gp[128];
};

__global__ __launch_bounds__(512, 2) void edge_mlp(
    const ushort* __restrict__ Pa, const ushort* __restrict__ Pb,
    const ushort* __restrict__ w2f, const ushort* __restrict__ w3f,
    const u32x4* __restrict__ packed, const int* __restrict__ base,
    int* __restrict__ queue,
    const float* __restrict__ W1, const float* __restrict__ b2,
    const float* __restrict__ b3, const float* __restrict__ W4,
    const float* __restrict__ b4, float* __restrict__ val_sorted,
    int NB, int NN) {
  __shared__ SMem s;
  __shared__ int sh_bid;
  const int tid = threadIdx.x;
  {
    const uint4* s2 = (const uint4*)w2f;
    const uint4* s3 = (const uint4*)w3f;
    uint4* d2 = (uint4*)s.w2;
    uint4* d3 = (uint4*)s.w3;
    for (int i = tid; i < 2048; i += 512) { d2[i] = s2[i]; d3[i] = s3[i]; }
    if (tid < 128) {
      s.b2[tid] = b2[tid]; s.b3[tid] = b3[tid]; s.w4[tid] = W4[tid];
      s.w1gp[fpos(tid)] = (ushort)f2bf(W1[256 * 128 + tid]);
    }
  }
  __syncthreads();

  const float b4v = b4[0];
  const int lane = tid & 63;
  const int c = lane & 15;
  const int q = lane >> 4;
  const int xcd = get_xcd();
  const int PART = (NN + 7) / 8;
  const f32x4 z4 = {0.f, 0.f, 0.f, 0.f};

  bh8 w1gb[4];
#pragma unroll
  for (int kf = 0; kf < 4; ++kf)
    w1gb[kf] = *(const bh8*)&s.w1gp[kf * 32 + q * 8];

  // staging ids for this thread (Pa slice copy)
  const int st_node = tid >> 4, st_seg = tid & 15;

  // own partition first, then steal (correct regardless of XCC mapping)
  for (int pp = 0; pp < 8; ++pp) {
    const int part = (xcd + pp) & 7;
    const int kb0 = (part == 0) ? 0 : (((part * PART) >> 5) << 1);
    const int kb1 = (part == 7) ? NB : ((((part + 1) * PART) >> 5) << 1);
    for (;;) {
      if (tid == 0) sh_bid = kb0 + atomicAdd(&queue[part], 1);
      __syncthreads();
      const int bid = sh_bid;
      __syncthreads();
      if (bid >= kb1) break;
      const int B0e = base[bid];
      const int B1e = base[bid + 1];
      const int src0 = (bid >> 1) * 32;
      // ---- stage Pa slice (8KB) into LDS, seg-swizzled ----
      {
        int ng = src0 + st_node;
        if (ng >= NN) ng = NN - 1;
        const uint4 v = *(const uint4*)(Pa + (size_t)ng * 128 + st_seg * 8);
        *(uint4*)&s.pa[st_node][(st_seg ^ (st_node & 15)) * 8] = v;
      }
      __syncthreads();
      const int nt = (B1e - B0e + 63) >> 6;
      for (int t = tid >> 6; t < nt; t += 8) {
        const int ebase = B0e + t * 64;

        int se[4], de[4];
        float gv[4];
#pragma unroll
        for (int et = 0; et < 4; ++et) {
          int e = ebase + et * 16 + c;
          if (e >= B1e) e = B1e - 1;
          u32x4 pk = packed[e];
          se[et] = (int)pk.x; de[et] = (int)pk.y;
          gv[et] = __uint_as_float(pk.z);
        }

        // ---- layer-1: bp = relu(PaLDS[src] + Pb[dst] + g*w1g) ----
        bh8 bp[4][4];
#pragma unroll
        for (int et = 0; et < 4; ++et) {
          const int node = se[et] - src0;
          const ushort* pbr = Pb + (size_t)de[et] * 128 + q * 8;
          bh8 pa8[4], pb8[4];
#pragma unroll
          for (int kf = 0; kf < 4; ++kf) {
            int seg = (q + 4 * kf) ^ (node & 15);
            pa8[kf] = *(const bh8*)&s.pa[node][seg * 8];
            pb8[kf] = *(const bh8*)(pbr + kf * 32);
          }
#pragma unroll
          for (int kf = 0; kf < 4; ++kf) {
            bh8 t8;
#pragma unroll
            for (int i = 0; i < 8; ++i) {
              float v = bf2f(pa8[kf][i]) + bf2f(pb8[kf][i]);
              v = fmaf(gv[et], bf2f(w1gb[kf][i]), v);
              t8[i] = f2bf(fmaxf(v, 0.f));
            }
            bp[et][kf] = t8;
          }
        }

        // ---- layer 2 ----
        f32x4 acc[4][8];
#pragma unroll
        for (int et = 0; et < 4; ++et)
#pragma unroll
          for (int ob = 0; ob < 8; ++ob) acc[et][ob] = z4;
#pragma unroll
        for (int kf = 0; kf < 4; ++kf) {
#pragma unroll
          for (int ob = 0; ob < 8; ++ob) {
            bh8 af = *(const bh8*)&s.w2[((ob * 4 + kf) * 64 + lane) * 8];
#pragma unroll
            for (int et = 0; et < 4; ++et)
              acc[et][ob] = __builtin_amdgcn_mfma_f32_16x16x32_bf16(af, bp[et][kf], acc[et][ob], 0, 0, 0);
          }
        }
#pragma unroll
        for (int et = 0; et < 4; ++et) {
#pragma unroll
          for (int kf = 0; kf < 4; ++kf) {
            bh8 t8;
#pragma unroll
            for (int half = 0; half < 2; ++half) {
              int ob = kf * 2 + half;
#pragma unroll
              for (int r = 0; r < 4; ++r) {
                int f = ob * 16 + q * 4 + r;
                float v = fmaxf(acc[et][ob][r] + s.b2[f], 0.f);
                t8[half * 4 + r] = f2bf(v);
              }
            }
            bp[et][kf] = t8;
          }
        }

        // ---- layer 3 ----
#pragma unroll
        for (int et = 0; et < 4; ++et)
#pragma unroll
          for (int ob = 0; ob < 8; ++ob) acc[et][ob] = z4;
#pragma unroll
        for (int kf = 0; kf < 4; ++kf) {
#pragma unroll
          for (int ob = 0; ob < 8; ++ob) {
            bh8 af = *(const bh8*)&s.w3[((ob * 4 + kf) * 64 + lane) * 8];
#pragma unroll
            for (int et = 0; et < 4; ++et)
              acc[et][ob] = __builtin_amdgcn_mfma_f32_16x16x32_bf16(af, bp[et][kf], acc[et][ob], 0, 0, 0);
          }
        }

        // ---- fused relu3 + layer 4 + sigmoid ----
        float psum[4] = {0.f, 0.f, 0.f, 0.f};
#pragma unroll
        for (int et = 0; et < 4; ++et) {
#pragma unroll
          for (int ob = 0; ob < 8; ++ob) {
#pragma unroll
            for (int r = 0; r < 4; ++r) {
              int f = ob * 16 + q * 4 + r;
              float v = fmaxf(acc[et][ob][r] + s.b3[f], 0.f);
              psum[et] += v * s.w4[f];
            }
          }
        }
#pragma unroll
        for (int et = 0; et < 4; ++et) {
          psum[et] += __shfl_xor(psum[et], 16, 64);
          psum[et] += __shfl_xor(psum[et], 32, 64);
        }
        float vsel = (q == 0) ? psum[0] : (q == 1) ? psum[1] : (q == 2) ? psum[2] : psum[3];
        float val = vsel + b4v;
        float sig = 1.0f / (1.0f + __expf(-val));
        int elin = ebase + q * 16 + c;
        if (elin < B1e) val_sorted[elin] = sig;   // sequential, coalesced
      }
      __syncthreads();   // before next bucket's Pa staging
    }
  }
}

// ---- kernel 7: unsort: out[i] = val_sorted[perm[i]] ----
__global__ __launch_bounds__(256) void unsort_k(
    const int* __restrict__ perm, const float* __restrict__ val_sorted,
    float* __restrict__ out, int E) {
  int i4 = (blockIdx.x * 256 + threadIdx.x) * 4;
  if (i4 + 3 < E) {
    int4 p = *(const int4*)(perm + i4);
    float4 v;
    v.x = val_sorted[p.x]; v.y = val_sorted[p.y];
    v.z = val_sorted[p.z]; v.w = val_sorted[p.w];
    *(float4*)(out + i4) = v;
  } else {
    for (int i = i4; i < E; ++i) out[i] = val_sorted[perm[i]];
  }
}

extern "C" void kernel_launch(void* const* d_in, const int* in_sizes, int n_in,
                              void* d_out, int out_size, void* d_ws, size_t ws_size,
                              hipStream_t stream) {
  const float* z     = (const float*)d_in[0];
  const float* graph = (const float*)d_in[2];
  const int*   ei    = (const int*)d_in[3];
  const float* W1 = (const float*)d_in[4];
  const float* b1 = (const float*)d_in[5];
  const float* W2 = (const float*)d_in[6];
  const float* b2 = (const float*)d_in[7];
  const float* W3 = (const float*)d_in[8];
  const float* b3 = (const float*)d_in[9];
  const float* W4 = (const float*)d_in[10];
  const float* b4 = (const float*)d_in[11];
  int E  = in_sizes[3] / 2;
  int NN = in_sizes[0] / 128;
  int NSB = (E + EPB - 1) / EPB;
  int NB = ((NN + 31) / 32) * 2;        // 626 for NN=10000 (<=1024 required)

  char* w = (char*)d_ws;
  size_t o = 0;
  auto alloc = [&](size_t bytes) { void* p = w + o; o = (o + bytes + 255) & ~(size_t)255; return p; };
  ushort* Pa     = (ushort*)alloc((size_t)NN * 128 * 2);
  ushort* Pb     = (ushort*)alloc((size_t)NN * 128 * 2);
  ushort* w2f    = (ushort*)alloc(16384 * 2);
  ushort* w3f    = (ushort*)alloc(16384 * 2);
  int*    H      = (int*)alloc((size_t)NSB * NB * 4);
  int*    total  = (int*)alloc((size_t)NB * 4);
  int*    base   = (int*)alloc((size_t)(NB + 1) * 4);
  int*    queue  = (int*)alloc(8 * 4);
  int*    perm   = (int*)alloc((size_t)E * 4);
  float*  vals   = (float*)alloc((size_t)E * 4);
  u32x4*  packed = (u32x4*)alloc((size_t)E * 16);

  hipLaunchKernelGGL(precompute_p, dim3((NN + 3) / 4), dim3(256), 0, stream,
                     z, W1, b1, Pa, Pb, NN);
  hipLaunchKernelGGL(pack_w, dim3(32), dim3(512), 0, stream, W2, W3, w2f, w3f);
  hipLaunchKernelGGL(histB, dim3(NSB), dim3(256), 0, stream, ei, H, E, NN, NB);
  hipLaunchKernelGGL(scanA, dim3((NB + 7) / 8), dim3(512), 0, stream, H, total, NB, NSB);
  hipLaunchKernelGGL(scanB, dim3(1), dim3(1024), 0, stream, total, base, queue, NB);
  hipLaunchKernelGGL(scatterB, dim3(NSB), dim3(256), 0, stream,
                     ei, graph, H, base, packed, perm, E, NN, NB);
  hipLaunchKernelGGL(edge_mlp, dim3(NBLOCKS_MAIN), dim3(512), 0, stream,
                     Pa, Pb, w2f, w3f, packed, base, queue, W1, b2, b3, W4, b4,
                     vals, NB, NN);
  hipLaunchKernelGGL(unsort_k, dim3((E / 4 + 255) / 256), dim3(256), 0, stream,
                     perm, vals, (float*)d_out, E);
}

// Round 11
// 216.468 us; speedup vs baseline: 1.7787x; 1.7787x over previous
//
#include <hip/hip_runtime.h>
#include <hip/hip_bf16.h>

typedef short bh8 __attribute__((ext_vector_type(8)));
typedef float f32x4 __attribute__((ext_vector_type(4)));
typedef uint u32x2 __attribute__((ext_vector_type(2)));

#define NBLOCKS_MAIN 512
#define EPB 4096           // edges per sort-block
#define MAXB 1280          // max buckets (LDS arrays)

__device__ __forceinline__ short f2bf(float f) {
  __hip_bfloat16 h = __float2bfloat16(f);
  return *reinterpret_cast<short*>(&h);
}
__device__ __forceinline__ float bf2f(short s) {
  return __uint_as_float(((uint)(ushort)s) << 16);
}
__device__ __forceinline__ int fpos(int f) {
  int kf = (f >> 5) & 3, h = (f >> 4) & 1, q = (f >> 2) & 3, j = f & 3;
  return (kf << 5) | (q << 3) | (h << 2) | j;
}
__device__ __forceinline__ int get_xcd() {
  uint x;
  asm volatile("s_getreg_b32 %0, hwreg(HW_REG_XCC_ID)" : "=s"(x));
  return (int)(x & 7u);
}

// ---- kernel 1: per-node Pa = z@W1a + b1, Pb = z@W1b, bf16 frag-permuted ----
__global__ __launch_bounds__(256) void precompute_p(
    const float* __restrict__ z, const float* __restrict__ W1,
    const float* __restrict__ b1, ushort* __restrict__ Pa,
    ushort* __restrict__ Pb, int NN) {
  __shared__ float zs[4][128];
  const int tid = threadIdx.x;
  const int n0 = blockIdx.x * 4;
  for (int i = tid; i < 512; i += 256) {
    int m = i >> 7, ff = i & 127, n = n0 + m;
    zs[m][ff] = (n < NN) ? z[n * 128 + ff] : 0.f;
  }
  __syncthreads();
  const int f = tid & 127;
  const bool isA = tid < 128;
  const float* w = W1 + (isA ? 0 : 128) * 128 + f;
  float a0, a1, a2, a3;
  a0 = a1 = a2 = a3 = isA ? b1[f] : 0.f;
#pragma unroll 16
  for (int k = 0; k < 128; ++k) {
    float wv = w[(size_t)k * 128];
    a0 += zs[0][k] * wv; a1 += zs[1][k] * wv;
    a2 += zs[2][k] * wv; a3 += zs[3][k] * wv;
  }
  ushort* dst = isA ? Pa : Pb;
  int pos = fpos(f);
  float av[4] = {a0, a1, a2, a3};
#pragma unroll
  for (int m = 0; m < 4; ++m)
    if (n0 + m < NN) dst[(size_t)(n0 + m) * 128 + pos] = (ushort)f2bf(av[m]);
}

// ---- kernel 2: pack W2/W3 into frag-linear bf16 ----
__global__ __launch_bounds__(512) void pack_w(
    const float* __restrict__ W2, const float* __restrict__ W3,
    ushort* __restrict__ w2f, ushort* __restrict__ w3f) {
  int idx = blockIdx.x * 512 + threadIdx.x;
  if (idx >= 16384) return;
  int e = idx & 7, l = (idx >> 3) & 63, kb = (idx >> 9) & 3, ob = idx >> 11;
  int q = l >> 4;
  int k = kb * 32 + (e < 4 ? q * 4 + e : 16 + q * 4 + (e - 4));
  int n = ob * 16 + (l & 15);
  w2f[idx] = (ushort)f2bf(W2[k * 128 + n]);
  w3f[idx] = (ushort)f2bf(W3[k * 128 + n]);
}

__device__ __forceinline__ int edge_key(int s, int d, int NN) {
  return ((s >> 5) << 1) | ((2 * d >= NN) ? 1 : 0);   // 32-node src buckets x dst half
}

// ---- kernel 3: per-block bucket histogram (LDS atomics only) ----
__global__ __launch_bounds__(256) void histB(
    const int* __restrict__ ei, int* __restrict__ H, int E, int NN, int NB) {
  __shared__ int h[MAXB];
  const int tid = threadIdx.x, j = blockIdx.x;
  for (int b = tid; b < NB; b += 256) h[b] = 0;
  __syncthreads();
#pragma unroll
  for (int r = 0; r < EPB / 256; ++r) {
    int e = j * EPB + r * 256 + tid;
    if (e < E) {
      int s = __builtin_nontemporal_load(ei + e);
      int d = __builtin_nontemporal_load(ei + E + e);
      atomicAdd(&h[edge_key(s, d, NN)], 1);
    }
  }
  __syncthreads();
  for (int b = tid; b < NB; b += 256) H[(size_t)j * NB + b] = h[b];
}

// ---- kernel 4a: per-bucket column exclusive scan over blocks (wave/bucket) ----
__global__ __launch_bounds__(512) void scanA(
    int* __restrict__ H, int* __restrict__ total, int NB, int NSB) {
  const int w = threadIdx.x >> 6, lane = threadIdx.x & 63;
  const int b = blockIdx.x * 8 + w;
  if (b >= NB) return;
  int run = 0;
  for (int base = 0; base < NSB; base += 64) {
    int j = base + lane;
    int v = (j < NSB) ? H[(size_t)j * NB + b] : 0;
    int inc = v;
#pragma unroll
    for (int dd = 1; dd < 64; dd <<= 1) {
      int u = __shfl_up(inc, dd, 64);
      if (lane >= dd) inc += u;
    }
    if (j < NSB) H[(size_t)j * NB + b] = run + inc - v;
    run += __shfl(inc, 63, 64);
  }
  if (lane == 0) total[b] = run;
}

// ---- kernel 4b: scan bucket totals -> base[]; queue reset ----
__global__ __launch_bounds__(1024) void scanB(
    const int* __restrict__ total, int* __restrict__ base,
    int* __restrict__ queue, int NB) {
  const int tid = threadIdx.x, lane = tid & 63, w = tid >> 6;
  __shared__ int wsum[16], woff[17];
  int v = (tid < NB) ? total[tid] : 0;   // NB <= 1024
  int inc = v;
#pragma unroll
  for (int dd = 1; dd < 64; dd <<= 1) {
    int u = __shfl_up(inc, dd, 64);
    if (lane >= dd) inc += u;
  }
  if (lane == 63) wsum[w] = inc;
  __syncthreads();
  if (tid == 0) {
    int a = 0;
#pragma unroll
    for (int k = 0; k < 16; ++k) { woff[k] = a; a += wsum[k]; }
    woff[16] = a;
  }
  __syncthreads();
  int ex = woff[w] + inc - v;
  if (tid <= NB) base[tid] = (tid < NB) ? ex : woff[16];
  if (tid < 8) queue[tid] = 0;
}

// ---- kernel 5: scatter into bucket order + pre-gather graph + perm ----
__global__ __launch_bounds__(256) void scatterB(
    const int* __restrict__ ei, const float* __restrict__ graph,
    const int* __restrict__ H, const int* __restrict__ base,
    u32x2* __restrict__ packed, int* __restrict__ perm,
    int E, int NN, int NB) {
  __shared__ int cur[MAXB];
  const int tid = threadIdx.x, j = blockIdx.x;
  for (int b = tid; b < NB; b += 256)
    cur[b] = H[(size_t)j * NB + b] + base[b];
  __syncthreads();
#pragma unroll
  for (int r = 0; r < EPB / 256; ++r) {
    int e = j * EPB + r * 256 + tid;
    if (e < E) {
      int s = __builtin_nontemporal_load(ei + e);
      int d = __builtin_nontemporal_load(ei + E + e);
      float g = __builtin_nontemporal_load(graph + (size_t)s * NN + d);
      int pos = atomicAdd(&cur[edge_key(s, d, NN)], 1);
      u32x2 pk = {((uint)s << 16) | (uint)d, __float_as_uint(g)};
      __builtin_nontemporal_store(pk, packed + pos);
      __builtin_nontemporal_store(pos, perm + e);
    }
  }
}

// ---- kernel 6: main edge MLP, tile-quantum XCD queues, nt streams ----
struct alignas(16) SMem {
  ushort w2[16384];      // frag-linear: ((ob*4+kf)*64+lane)*8+e
  ushort w3[16384];
  float b2[128], b3[128], w4[128];
  ushort w1gp[128];
};

__global__ __launch_bounds__(512, 2) void edge_mlp(
    const ushort* __restrict__ Pa, const ushort* __restrict__ Pb,
    const ushort* __restrict__ w2f, const ushort* __restrict__ w3f,
    const u32x2* __restrict__ packed, const int* __restrict__ base,
    int* __restrict__ queue,
    const float* __restrict__ W1, const float* __restrict__ b2,
    const float* __restrict__ b3, const float* __restrict__ W4,
    const float* __restrict__ b4, float* __restrict__ val_sorted,
    int NB, int NN) {
  __shared__ SMem s;
  __shared__ int sh_tb;
  const int tid = threadIdx.x;
  {
    const uint4* s2 = (const uint4*)w2f;
    const uint4* s3 = (const uint4*)w3f;
    uint4* d2 = (uint4*)s.w2;
    uint4* d3 = (uint4*)s.w3;
    for (int i = tid; i < 2048; i += 512) { d2[i] = s2[i]; d3[i] = s3[i]; }
    if (tid < 128) {
      s.b2[tid] = b2[tid]; s.b3[tid] = b3[tid]; s.w4[tid] = W4[tid];
      s.w1gp[fpos(tid)] = (ushort)f2bf(W1[256 * 128 + tid]);
    }
  }
  __syncthreads();

  const float b4v = b4[0];
  const int lane = tid & 63;
  const int c = lane & 15;
  const int q = lane >> 4;
  const int xcd = get_xcd();
  const int PART = (NN + 7) / 8;
  const f32x4 z4 = {0.f, 0.f, 0.f, 0.f};

  bh8 w1gb[4];
#pragma unroll
  for (int kf = 0; kf < 4; ++kf)
    w1gb[kf] = *(const bh8*)&s.w1gp[kf * 32 + q * 8];

  // own partition first, then steal (correct regardless of XCC mapping)
  for (int pp = 0; pp < 8; ++pp) {
    const int part = (xcd + pp) & 7;
    const int kb0 = (part == 0) ? 0 : (((part * PART) >> 5) << 1);
    const int kb1 = (part == 7) ? NB : ((((part + 1) * PART) >> 5) << 1);
    const int B0 = base[kb0];
    const int B1 = base[kb1];
    const int ptiles = (B1 - B0 + 63) >> 6;
    for (;;) {
      if (tid == 0) sh_tb = atomicAdd(&queue[part], 8);
      __syncthreads();
      const int tb = sh_tb;
      __syncthreads();
      if (tb >= ptiles) break;
      const int t = tb + (tid >> 6);
      if (t < ptiles) {
        const int ebase = B0 + t * 64;

        int se[4], de[4];
        float gv[4];
#pragma unroll
        for (int et = 0; et < 4; ++et) {
          int e = ebase + et * 16 + c;
          if (e >= B1) e = B1 - 1;
          u32x2 pk = __builtin_nontemporal_load(packed + e);
          se[et] = (int)(pk.x >> 16); de[et] = (int)(pk.x & 0xffffu);
          gv[et] = __uint_as_float(pk.y);
        }

        // ---- layer-1: bp = relu(Pa[src] + Pb[dst] + g*w1g) ----
        bh8 bp[4][4];
#pragma unroll
        for (int et = 0; et < 4; ++et) {
          const ushort* par = Pa + (size_t)se[et] * 128 + q * 8;
          const ushort* pbr = Pb + (size_t)de[et] * 128 + q * 8;
          bh8 pa8[4], pb8[4];
#pragma unroll
          for (int kf = 0; kf < 4; ++kf) {
            pa8[kf] = *(const bh8*)(par + kf * 32);
            pb8[kf] = *(const bh8*)(pbr + kf * 32);
          }
#pragma unroll
          for (int kf = 0; kf < 4; ++kf) {
            bh8 t8;
#pragma unroll
            for (int i = 0; i < 8; ++i) {
              float v = bf2f(pa8[kf][i]) + bf2f(pb8[kf][i]);
              v = fmaf(gv[et], bf2f(w1gb[kf][i]), v);
              t8[i] = f2bf(fmaxf(v, 0.f));
            }
            bp[et][kf] = t8;
          }
        }

        // ---- layer 2 ----
        f32x4 acc[4][8];
#pragma unroll
        for (int et = 0; et < 4; ++et)
#pragma unroll
          for (int ob = 0; ob < 8; ++ob) acc[et][ob] = z4;
#pragma unroll
        for (int kf = 0; kf < 4; ++kf) {
#pragma unroll
          for (int ob = 0; ob < 8; ++ob) {
            bh8 af = *(const bh8*)&s.w2[((ob * 4 + kf) * 64 + lane) * 8];
#pragma unroll
            for (int et = 0; et < 4; ++et)
              acc[et][ob] = __builtin_amdgcn_mfma_f32_16x16x32_bf16(af, bp[et][kf], acc[et][ob], 0, 0, 0);
          }
        }
#pragma unroll
        for (int et = 0; et < 4; ++et) {
#pragma unroll
          for (int kf = 0; kf < 4; ++kf) {
            bh8 t8;
#pragma unroll
            for (int half = 0; half < 2; ++half) {
              int ob = kf * 2 + half;
#pragma unroll
              for (int r = 0; r < 4; ++r) {
                int f = ob * 16 + q * 4 + r;
                float v = fmaxf(acc[et][ob][r] + s.b2[f], 0.f);
                t8[half * 4 + r] = f2bf(v);
              }
            }
            bp[et][kf] = t8;
          }
        }

        // ---- layer 3 ----
#pragma unroll
        for (int et = 0; et < 4; ++et)
#pragma unroll
          for (int ob = 0; ob < 8; ++ob) acc[et][ob] = z4;
#pragma unroll
        for (int kf = 0; kf < 4; ++kf) {
#pragma unroll
          for (int ob = 0; ob < 8; ++ob) {
            bh8 af = *(const bh8*)&s.w3[((ob * 4 + kf) * 64 + lane) * 8];
#pragma unroll
            for (int et = 0; et < 4; ++et)
              acc[et][ob] = __builtin_amdgcn_mfma_f32_16x16x32_bf16(af, bp[et][kf], acc[et][ob], 0, 0, 0);
          }
        }

        // ---- fused relu3 + layer 4 + sigmoid ----
        float psum[4] = {0.f, 0.f, 0.f, 0.f};
#pragma unroll
        for (int et = 0; et < 4; ++et) {
#pragma unroll
          for (int ob = 0; ob < 8; ++ob) {
#pragma unroll
            for (int r = 0; r < 4; ++r) {
              int f = ob * 16 + q * 4 + r;
              float v = fmaxf(acc[et][ob][r] + s.b3[f], 0.f);
              psum[et] += v * s.w4[f];
            }
          }
        }
#pragma unroll
        for (int et = 0; et < 4; ++et) {
          psum[et] += __shfl_xor(psum[et], 16, 64);
          psum[et] += __shfl_xor(psum[et], 32, 64);
        }
        float vsel = (q == 0) ? psum[0] : (q == 1) ? psum[1] : (q == 2) ? psum[2] : psum[3];
        float val = vsel + b4v;
        float sig = 1.0f / (1.0f + __expf(-val));
        int elin = ebase + q * 16 + c;
        if (elin < B1) __builtin_nontemporal_store(sig, val_sorted + elin);
      }
    }
  }
}

// ---- kernel 7: unsort: out[i] = val_sorted[perm[i]] ----
__global__ __launch_bounds__(256) void unsort_k(
    const int* __restrict__ perm, const float* __restrict__ val_sorted,
    float* __restrict__ out, int E) {
  int i4 = (blockIdx.x * 256 + threadIdx.x) * 4;
  if (i4 + 3 < E) {
    int4 p = *(const int4*)(perm + i4);
    f32x4 v;
    v[0] = val_sorted[p.x]; v[1] = val_sorted[p.y];
    v[2] = val_sorted[p.z]; v[3] = val_sorted[p.w];
    __builtin_nontemporal_store(v, (f32x4*)(out + i4));
  } else {
    for (int i = i4; i < E; ++i) out[i] = val_sorted[perm[i]];
  }
}

extern "C" void kernel_launch(void* const* d_in, const int* in_sizes, int n_in,
                              void* d_out, int out_size, void* d_ws, size_t ws_size,
                              hipStream_t stream) {
  const float* z     = (const float*)d_in[0];
  const float* graph = (const float*)d_in[2];
  const int*   ei    = (const int*)d_in[3];
  const float* W1 = (const float*)d_in[4];
  const float* b1 = (const float*)d_in[5];
  const float* W2 = (const float*)d_in[6];
  const float* b2 = (const float*)d_in[7];
  const float* W3 = (const float*)d_in[8];
  const float* b3 = (const float*)d_in[9];
  const float* W4 = (const float*)d_in[10];
  const float* b4 = (const float*)d_in[11];
  int E  = in_sizes[3] / 2;
  int NN = in_sizes[0] / 128;
  int NSB = (E + EPB - 1) / EPB;
  int NB = ((NN + 31) / 32) * 2;        // 626 for NN=10000 (<=1024 required)

  char* w = (char*)d_ws;
  size_t o = 0;
  auto alloc = [&](size_t bytes) { void* p = w + o; o = (o + bytes + 255) & ~(size_t)255; return p; };
  ushort* Pa     = (ushort*)alloc((size_t)NN * 128 * 2);
  ushort* Pb     = (ushort*)alloc((size_t)NN * 128 * 2);
  ushort* w2f    = (ushort*)alloc(16384 * 2);
  ushort* w3f    = (ushort*)alloc(16384 * 2);
  int*    H      = (int*)alloc((size_t)NSB * NB * 4);
  int*    total  = (int*)alloc((size_t)NB * 4);
  int*    base   = (int*)alloc((size_t)(NB + 1) * 4);
  int*    queue  = (int*)alloc(8 * 4);
  int*    perm   = (int*)alloc((size_t)E * 4);
  float*  vals   = (float*)alloc((size_t)E * 4);
  u32x2*  packed = (u32x2*)alloc((size_t)E * 8);

  hipLaunchKernelGGL(precompute_p, dim3((NN + 3) / 4), dim3(256), 0, stream,
                     z, W1, b1, Pa, Pb, NN);
  hipLaunchKernelGGL(pack_w, dim3(32), dim3(512), 0, stream, W2, W3, w2f, w3f);
  hipLaunchKernelGGL(histB, dim3(NSB), dim3(256), 0, stream, ei, H, E, NN, NB);
  hipLaunchKernelGGL(scanA, dim3((NB + 7) / 8), dim3(512), 0, stream, H, total, NB, NSB);
  hipLaunchKernelGGL(scanB, dim3(1), dim3(1024), 0, stream, total, base, queue, NB);
  hipLaunchKernelGGL(scatterB, dim3(NSB), dim3(256), 0, stream,
                     ei, graph, H, base, packed, perm, E, NN, NB);
  hipLaunchKernelGGL(edge_mlp, dim3(NBLOCKS_MAIN), dim3(512), 0, stream,
                     Pa, Pb, w2f, w3f, packed, base, queue, W1, b2, b3, W4, b4,
                     vals, NB, NN);
  hipLaunchKernelGGL(unsort_k, dim3((E / 4 + 255) / 256), dim3(256), 0, stream,
                     perm, vals, (float*)d_out, E);
}

// Round 12
// 200.479 us; speedup vs baseline: 1.9206x; 1.0798x over previous
//
#include <hip/hip_runtime.h>
#include <hip/hip_bf16.h>

typedef short bh8 __attribute__((ext_vector_type(8)));
typedef float f32x4 __attribute__((ext_vector_type(4)));
typedef uint u32x2 __attribute__((ext_vector_type(2)));

#define NBLOCKS_MAIN 512
#define EPB 2048           // edges per sort-block
#define NBUCK 64           // 8 src-parts x 8 dst-groups

__device__ __forceinline__ short f2bf(float f) {
  __hip_bfloat16 h = __float2bfloat16(f);
  return *reinterpret_cast<short*>(&h);
}
__device__ __forceinline__ float bf2f(short s) {
  return __uint_as_float(((uint)(ushort)s) << 16);
}
__device__ __forceinline__ int fpos(int f) {
  int kf = (f >> 5) & 3, h = (f >> 4) & 1, q = (f >> 2) & 3, j = f & 3;
  return (kf << 5) | (q << 3) | (h << 2) | j;
}
__device__ __forceinline__ int get_xcd() {
  uint x;
  asm volatile("s_getreg_b32 %0, hwreg(HW_REG_XCC_ID)" : "=s"(x));
  return (int)(x & 7u);
}

// ---- kernel 1: per-node Pa = z@W1a + b1, Pb = z@W1b, bf16 frag-permuted ----
__global__ __launch_bounds__(256) void precompute_p(
    const float* __restrict__ z, const float* __restrict__ W1,
    const float* __restrict__ b1, ushort* __restrict__ Pa,
    ushort* __restrict__ Pb, int NN) {
  __shared__ float zs[4][128];
  const int tid = threadIdx.x;
  const int n0 = blockIdx.x * 4;
  for (int i = tid; i < 512; i += 256) {
    int m = i >> 7, ff = i & 127, n = n0 + m;
    zs[m][ff] = (n < NN) ? z[n * 128 + ff] : 0.f;
  }
  __syncthreads();
  const int f = tid & 127;
  const bool isA = tid < 128;
  const float* w = W1 + (isA ? 0 : 128) * 128 + f;
  float a0, a1, a2, a3;
  a0 = a1 = a2 = a3 = isA ? b1[f] : 0.f;
#pragma unroll 16
  for (int k = 0; k < 128; ++k) {
    float wv = w[(size_t)k * 128];
    a0 += zs[0][k] * wv; a1 += zs[1][k] * wv;
    a2 += zs[2][k] * wv; a3 += zs[3][k] * wv;
  }
  ushort* dst = isA ? Pa : Pb;
  int pos = fpos(f);
  float av[4] = {a0, a1, a2, a3};
#pragma unroll
  for (int m = 0; m < 4; ++m)
    if (n0 + m < NN) dst[(size_t)(n0 + m) * 128 + pos] = (ushort)f2bf(av[m]);
}

// ---- kernel 2: pack W2/W3 into frag-linear bf16 ----
__global__ __launch_bounds__(512) void pack_w(
    const float* __restrict__ W2, const float* __restrict__ W3,
    ushort* __restrict__ w2f, ushort* __restrict__ w3f) {
  int idx = blockIdx.x * 512 + threadIdx.x;
  if (idx >= 16384) return;
  int e = idx & 7, l = (idx >> 3) & 63, kb = (idx >> 9) & 3, ob = idx >> 11;
  int q = l >> 4;
  int k = kb * 32 + (e < 4 ? q * 4 + e : 16 + q * 4 + (e - 4));
  int n = ob * 16 + (l & 15);
  w2f[idx] = (ushort)f2bf(W2[k * 128 + n]);
  w3f[idx] = (ushort)f2bf(W3[k * 128 + n]);
}

__device__ __forceinline__ int edge_key(int s, int d, int sdiv) {
  return (s / sdiv) * 8 + (d / sdiv);   // 8 src-parts x 8 dst-groups
}

// ---- kernel 3: per-block 64-bucket histogram (LDS atomics only) ----
__global__ __launch_bounds__(256) void hist64(
    const int* __restrict__ ei, int* __restrict__ H, int E, int sdiv, int NSB) {
  __shared__ int h[NBUCK];
  const int tid = threadIdx.x, j = blockIdx.x;
  if (tid < NBUCK) h[tid] = 0;
  __syncthreads();
#pragma unroll
  for (int r = 0; r < EPB / 256; ++r) {
    int e = j * EPB + r * 256 + tid;
    if (e < E) {
      int s = __builtin_nontemporal_load(ei + e);
      int d = __builtin_nontemporal_load(ei + E + e);
      atomicAdd(&h[edge_key(s, d, sdiv)], 1);
    }
  }
  __syncthreads();
  if (tid < NBUCK) H[(size_t)tid * NSB + j] = h[tid];   // bucket-major
}

// ---- kernel 4a: per-bucket exclusive scan over blocks (wave per bucket) ----
__global__ __launch_bounds__(512) void scanA(
    int* __restrict__ H, int* __restrict__ total, int NSB) {
  const int w = threadIdx.x >> 6, lane = threadIdx.x & 63;
  const int b = blockIdx.x * 8 + w;
  if (b >= NBUCK) return;
  int run = 0;
  for (int base = 0; base < NSB; base += 64) {
    int j = base + lane;
    int v = (j < NSB) ? H[(size_t)b * NSB + j] : 0;
    int inc = v;
#pragma unroll
    for (int dd = 1; dd < 64; dd <<= 1) {
      int u = __shfl_up(inc, dd, 64);
      if (lane >= dd) inc += u;
    }
    if (j < NSB) H[(size_t)b * NSB + j] = run + inc - v;
    run += __shfl(inc, 63, 64);
  }
  if (lane == 0) total[b] = run;
}

// ---- kernel 4b: exclusive scan of 64 totals -> base[]; queue reset ----
__global__ __launch_bounds__(64) void scanB(
    const int* __restrict__ total, int* __restrict__ base,
    int* __restrict__ queue) {
  const int lane = threadIdx.x;
  int v = total[lane];
  int inc = v;
#pragma unroll
  for (int dd = 1; dd < 64; dd <<= 1) {
    int u = __shfl_up(inc, dd, 64);
    if (lane >= dd) inc += u;
  }
  base[lane] = inc - v;
  if (lane == 63) base[64] = inc;
  if (lane < 8) queue[lane] = 0;
}

// ---- kernel 5: scatter into bucket order + pre-gather graph + perm ----
__global__ __launch_bounds__(256) void scatter64(
    const int* __restrict__ ei, const float* __restrict__ graph,
    const int* __restrict__ H, const int* __restrict__ base,
    u32x2* __restrict__ packed, int* __restrict__ perm,
    int E, int NN, int sdiv, int NSB) {
  __shared__ int cur[NBUCK];
  const int tid = threadIdx.x, j = blockIdx.x;
  if (tid < NBUCK) cur[tid] = H[(size_t)tid * NSB + j] + base[tid];
  __syncthreads();
#pragma unroll
  for (int r = 0; r < EPB / 256; ++r) {
    int e = j * EPB + r * 256 + tid;
    if (e < E) {
      int s = __builtin_nontemporal_load(ei + e);
      int d = __builtin_nontemporal_load(ei + E + e);
      float g = __builtin_nontemporal_load(graph + (size_t)s * NN + d);
      int pos = atomicAdd(&cur[edge_key(s, d, sdiv)], 1);
      u32x2 pk = {((uint)s << 16) | (uint)d, __float_as_uint(g)};
      __builtin_nontemporal_store(pk, packed + pos);
      __builtin_nontemporal_store(pos, perm + e);
    }
  }
}

// ---- kernel 6: main edge MLP, tile-quantum XCD queues ----
struct alignas(16) SMem {
  ushort w2[16384];      // frag-linear: ((ob*4+kf)*64+lane)*8+e
  ushort w3[16384];
  float b2[128], b3[128], w4[128];
  ushort w1gp[128];
};

__global__ __launch_bounds__(512, 2) void edge_mlp(
    const ushort* __restrict__ Pa, const ushort* __restrict__ Pb,
    const ushort* __restrict__ w2f, const ushort* __restrict__ w3f,
    const u32x2* __restrict__ packed, const int* __restrict__ base,
    int* __restrict__ queue,
    const float* __restrict__ W1, const float* __restrict__ b2,
    const float* __restrict__ b3, const float* __restrict__ W4,
    const float* __restrict__ b4, float* __restrict__ val_sorted) {
  __shared__ SMem s;
  __shared__ int sh_tb;
  const int tid = threadIdx.x;
  {
    const uint4* s2 = (const uint4*)w2f;
    const uint4* s3 = (const uint4*)w3f;
    uint4* d2 = (uint4*)s.w2;
    uint4* d3 = (uint4*)s.w3;
    for (int i = tid; i < 2048; i += 512) { d2[i] = s2[i]; d3[i] = s3[i]; }
    if (tid < 128) {
      s.b2[tid] = b2[tid]; s.b3[tid] = b3[tid]; s.w4[tid] = W4[tid];
      s.w1gp[fpos(tid)] = (ushort)f2bf(W1[256 * 128 + tid]);
    }
  }
  __syncthreads();

  const float b4v = b4[0];
  const int lane = tid & 63;
  const int c = lane & 15;
  const int q = lane >> 4;
  const int xcd = get_xcd();
  const f32x4 z4 = {0.f, 0.f, 0.f, 0.f};

  bh8 w1gb[4];
#pragma unroll
  for (int kf = 0; kf < 4; ++kf)
    w1gb[kf] = *(const bh8*)&s.w1gp[kf * 32 + q * 8];

  // own src-partition first (8 buckets, dst-ordered), then steal
  for (int pp = 0; pp < 8; ++pp) {
    const int part = (xcd + pp) & 7;
    const int B0 = base[part * 8];
    const int B1 = base[part * 8 + 8];
    const int ptiles = (B1 - B0 + 63) >> 6;
    for (;;) {
      if (tid == 0) sh_tb = atomicAdd(&queue[part], 8);
      __syncthreads();
      const int tb = sh_tb;
      __syncthreads();
      if (tb >= ptiles) break;
      const int t = tb + (tid >> 6);
      if (t < ptiles) {
        const int ebase = B0 + t * 64;

        int se[4], de[4];
        float gv[4];
#pragma unroll
        for (int et = 0; et < 4; ++et) {
          int e = ebase + et * 16 + c;
          if (e >= B1) e = B1 - 1;
          u32x2 pk = __builtin_nontemporal_load(packed + e);
          se[et] = (int)(pk.x >> 16); de[et] = (int)(pk.x & 0xffffu);
          gv[et] = __uint_as_float(pk.y);
        }

        // ---- layer-1: bp = relu(Pa[src] + Pb[dst] + g*w1g) ----
        bh8 bp[4][4];
#pragma unroll
        for (int et = 0; et < 4; ++et) {
          const ushort* par = Pa + (size_t)se[et] * 128 + q * 8;
          const ushort* pbr = Pb + (size_t)de[et] * 128 + q * 8;
          bh8 pa8[4], pb8[4];
#pragma unroll
          for (int kf = 0; kf < 4; ++kf) {
            pa8[kf] = *(const bh8*)(par + kf * 32);
            pb8[kf] = *(const bh8*)(pbr + kf * 32);
          }
#pragma unroll
          for (int kf = 0; kf < 4; ++kf) {
            bh8 t8;
#pragma unroll
            for (int i = 0; i < 8; ++i) {
              float v = bf2f(pa8[kf][i]) + bf2f(pb8[kf][i]);
              v = fmaf(gv[et], bf2f(w1gb[kf][i]), v);
              t8[i] = f2bf(fmaxf(v, 0.f));
            }
            bp[et][kf] = t8;
          }
        }

        // ---- layer 2 ----
        f32x4 acc[4][8];
#pragma unroll
        for (int et = 0; et < 4; ++et)
#pragma unroll
          for (int ob = 0; ob < 8; ++ob) acc[et][ob] = z4;
#pragma unroll
        for (int kf = 0; kf < 4; ++kf) {
#pragma unroll
          for (int ob = 0; ob < 8; ++ob) {
            bh8 af = *(const bh8*)&s.w2[((ob * 4 + kf) * 64 + lane) * 8];
#pragma unroll
            for (int et = 0; et < 4; ++et)
              acc[et][ob] = __builtin_amdgcn_mfma_f32_16x16x32_bf16(af, bp[et][kf], acc[et][ob], 0, 0, 0);
          }
        }
#pragma unroll
        for (int et = 0; et < 4; ++et) {
#pragma unroll
          for (int kf = 0; kf < 4; ++kf) {
            bh8 t8;
#pragma unroll
            for (int half = 0; half < 2; ++half) {
              int ob = kf * 2 + half;
#pragma unroll
              for (int r = 0; r < 4; ++r) {
                int f = ob * 16 + q * 4 + r;
                float v = fmaxf(acc[et][ob][r] + s.b2[f], 0.f);
                t8[half * 4 + r] = f2bf(v);
              }
            }
            bp[et][kf] = t8;
          }
        }

        // ---- layer 3 ----
#pragma unroll
        for (int et = 0; et < 4; ++et)
#pragma unroll
          for (int ob = 0; ob < 8; ++ob) acc[et][ob] = z4;
#pragma unroll
        for (int kf = 0; kf < 4; ++kf) {
#pragma unroll
          for (int ob = 0; ob < 8; ++ob) {
            bh8 af = *(const bh8*)&s.w3[((ob * 4 + kf) * 64 + lane) * 8];
#pragma unroll
            for (int et = 0; et < 4; ++et)
              acc[et][ob] = __builtin_amdgcn_mfma_f32_16x16x32_bf16(af, bp[et][kf], acc[et][ob], 0, 0, 0);
          }
        }

        // ---- fused relu3 + layer 4 + sigmoid ----
        float psum[4] = {0.f, 0.f, 0.f, 0.f};
#pragma unroll
        for (int et = 0; et < 4; ++et) {
#pragma unroll
          for (int ob = 0; ob < 8; ++ob) {
#pragma unroll
            for (int r = 0; r < 4; ++r) {
              int f = ob * 16 + q * 4 + r;
              float v = fmaxf(acc[et][ob][r] + s.b3[f], 0.f);
              psum[et] += v * s.w4[f];
            }
          }
        }
#pragma unroll
        for (int et = 0; et < 4; ++et) {
          psum[et] += __shfl_xor(psum[et], 16, 64);
          psum[et] += __shfl_xor(psum[et], 32, 64);
        }
        float vsel = (q == 0) ? psum[0] : (q == 1) ? psum[1] : (q == 2) ? psum[2] : psum[3];
        float val = vsel + b4v;
        float sig = 1.0f / (1.0f + __expf(-val));
        int elin = ebase + q * 16 + c;
        if (elin < B1) __builtin_nontemporal_store(sig, val_sorted + elin);
      }
    }
  }
}

// ---- kernel 7: unsort: out[i] = val_sorted[perm[i]] ----
__global__ __launch_bounds__(256) void unsort_k(
    const int* __restrict__ perm, const float* __restrict__ val_sorted,
    float* __restrict__ out, int E) {
  int i4 = (blockIdx.x * 256 + threadIdx.x) * 4;
  if (i4 + 3 < E) {
    int4 p = *(const int4*)(perm + i4);
    f32x4 v;
    v[0] = val_sorted[p.x]; v[1] = val_sorted[p.y];
    v[2] = val_sorted[p.z]; v[3] = val_sorted[p.w];
    __builtin_nontemporal_store(v, (f32x4*)(out + i4));
  } else {
    for (int i = i4; i < E; ++i) out[i] = val_sorted[perm[i]];
  }
}

extern "C" void kernel_launch(void* const* d_in, const int* in_sizes, int n_in,
                              void* d_out, int out_size, void* d_ws, size_t ws_size,
                              hipStream_t stream) {
  const float* z     = (const float*)d_in[0];
  const float* graph = (const float*)d_in[2];
  const int*   ei    = (const int*)d_in[3];
  const float* W1 = (const float*)d_in[4];
  const float* b1 = (const float*)d_in[5];
  const float* W2 = (const float*)d_in[6];
  const float* b2 = (const float*)d_in[7];
  const float* W3 = (const float*)d_in[8];
  const float* b3 = (const float*)d_in[9];
  const float* W4 = (const float*)d_in[10];
  const float* b4 = (const float*)d_in[11];
  int E  = in_sizes[3] / 2;
  int NN = in_sizes[0] / 128;
  int NSB = (E + EPB - 1) / EPB;
  int sdiv = (NN + 7) / 8;

  char* w = (char*)d_ws;
  size_t o = 0;
  auto alloc = [&](size_t bytes) { void* p = w + o; o = (o + bytes + 255) & ~(size_t)255; return p; };
  ushort* Pa     = (ushort*)alloc((size_t)NN * 128 * 2);
  ushort* Pb     = (ushort*)alloc((size_t)NN * 128 * 2);
  ushort* w2f    = (ushort*)alloc(16384 * 2);
  ushort* w3f    = (ushort*)alloc(16384 * 2);
  int*    H      = (int*)alloc((size_t)NBUCK * NSB * 4);
  int*    total  = (int*)alloc((size_t)NBUCK * 4);
  int*    base   = (int*)alloc((size_t)(NBUCK + 1) * 4);
  int*    queue  = (int*)alloc(8 * 4);
  int*    perm   = (int*)alloc((size_t)E * 4);
  float*  vals   = (float*)alloc((size_t)E * 4);
  u32x2*  packed = (u32x2*)alloc((size_t)E * 8);

  hipLaunchKernelGGL(precompute_p, dim3((NN + 3) / 4), dim3(256), 0, stream,
                     z, W1, b1, Pa, Pb, NN);
  hipLaunchKernelGGL(pack_w, dim3(32), dim3(512), 0, stream, W2, W3, w2f, w3f);
  hipLaunchKernelGGL(hist64, dim3(NSB), dim3(256), 0, stream, ei, H, E, sdiv, NSB);
  hipLaunchKernelGGL(scanA, dim3(8), dim3(512), 0, stream, H, total, NSB);
  hipLaunchKernelGGL(scanB, dim3(1), dim3(64), 0, stream, total, base, queue);
  hipLaunchKernelGGL(scatter64, dim3(NSB), dim3(256), 0, stream,
                     ei, graph, H, base, packed, perm, E, NN, sdiv, NSB);
  hipLaunchKernelGGL(edge_mlp, dim3(NBLOCKS_MAIN), dim3(512), 0, stream,
                     Pa, Pb, w2f, w3f, packed, base, queue, W1, b2, b3, W4, b4,
                     vals);
  hipLaunchKernelGGL(unsort_k, dim3((E / 4 + 255) / 256), dim3(256), 0, stream,
                     perm, vals, (float*)d_out, E);
}